// Round 11
// baseline (634.292 us; speedup 1.0000x reference)
//
#include <hip/hip_runtime.h>

// ---------------------------------------------------------------------------
// HedgeHog attention distillation map: pred = (fq.fk^T) rownorm, true = softmax(q0.k0^T/8)
// Output [2,2,16,2048,2048] fp32 = 1.07 GiB -> HBM-write-bound (~165us floor).
//
// v11: producer cadence = store rate. v10 (depth-1 reg prefetch) left the
// producer period = 1x operand-load latency (~2.2us under write traffic).
// Now: operands staged ONCE per block into LDS via async global_load_lds,
// TRANSPOSED ([colchunk][key]) through per-lane src-address permutation so
// fragment ds_reads are conflict-free. Ring-3 operand buffer = 2 chunks in
// flight (counted vmcnt(4)/(2), never 0, never touching a store). Storer
// waves stay pure-store. 67 matched raw s_barriers, no __syncthreads in loop.
// ---------------------------------------------------------------------------

typedef __attribute__((ext_vector_type(8))) short  bf16x8;
typedef __attribute__((ext_vector_type(4))) float  f32x4;

#define NN 2048
#define NBH 32

__device__ float g_part[NBH * 8 * 128];   // fk colsum partials
__device__ float g_normP[NBH * NN];       // 1 / pred row sum
__device__ float g_normT[NBH * NN];       // 1 / true row sum

__device__ __forceinline__ float bf2f(unsigned short u) {
  union { unsigned int i; float f; } v; v.i = ((unsigned int)u) << 16; return v.f;
}
__device__ __forceinline__ unsigned short f2bf(float f) {
  union { float f; unsigned int i; } v; v.f = f;
  unsigned int x = v.i;
  return (unsigned short)((x + 0x7FFFu + ((x >> 16) & 1u)) >> 16);  // RNE
}
__device__ __forceinline__ bf16x8 cvt8(const float* __restrict__ p) {
  bf16x8 v;
#pragma unroll
  for (int i = 0; i < 8; i++) v[i] = (short)f2bf(p[i]);
  return v;
}
__device__ __forceinline__ f32x4 mfma16(bf16x8 a, bf16x8 b, f32x4 c) {
  return __builtin_amdgcn_mfma_f32_16x16x32_bf16(a, b, c, 0, 0, 0);
}

// ---------------------------------------------------------------------------
// Kernel 1: projections + hedgehog features. One wave owns 16 rows.
// ---------------------------------------------------------------------------
__device__ __forceinline__ void proj_chain(
    const bf16x8 ax[2],
    const float* __restrict__ W1, const float* __restrict__ b1,
    const float* __restrict__ W2, const float* __restrict__ b2,
    unsigned short* __restrict__ o1w, unsigned short* __restrict__ o2w,
    unsigned short (*Tq)[72], unsigned short (*Tf)[136],
    long r0, int l15, int g, int l)
{
#pragma unroll
  for (int nt = 0; nt < 4; nt++) {
    f32x4 acc = {0.f, 0.f, 0.f, 0.f};
    acc = mfma16(ax[0], cvt8(W1 + (nt * 16 + l15) * 64 + g * 8), acc);
    acc = mfma16(ax[1], cvt8(W1 + (nt * 16 + l15) * 64 + 32 + g * 8), acc);
    float bv = b1[nt * 16 + l15];
#pragma unroll
    for (int j = 0; j < 4; j++)
      Tq[g * 4 + j][nt * 16 + l15] = f2bf(acc[j] + bv);   // C layout: row=(l>>4)*4+j, col=l&15
  }
#pragma unroll
  for (int i = 0; i < 2; i++) {
    int c = i * 64 + l;
    int r = c >> 3, cc = c & 7;
    *(bf16x8*)(o1w + (r0 + r) * 64 + cc * 8) = *(const bf16x8*)&Tq[r][cc * 8];
  }
  bf16x8 a1[2];
#pragma unroll
  for (int kk = 0; kk < 2; kk++)
    a1[kk] = *(const bf16x8*)&Tq[l15][kk * 32 + g * 8];
#pragma unroll
  for (int nt = 0; nt < 4; nt++) {
    f32x4 acc = {0.f, 0.f, 0.f, 0.f};
    acc = mfma16(a1[0], cvt8(W2 + (nt * 16 + l15) * 64 + g * 8), acc);
    acc = mfma16(a1[1], cvt8(W2 + (nt * 16 + l15) * 64 + 32 + g * 8), acc);
    float bv = b2[nt * 16 + l15];
#pragma unroll
    for (int j = 0; j < 4; j++) {
      float h = acc[j] + bv;
      Tf[g * 4 + j][nt * 16 + l15]      = f2bf(__expf(h));
      Tf[g * 4 + j][64 + nt * 16 + l15] = f2bf(__expf(-h));
    }
  }
#pragma unroll
  for (int i = 0; i < 4; i++) {
    int c = i * 64 + l;
    int r = c >> 4, cc = c & 15;
    *(bf16x8*)(o2w + (r0 + r) * 128 + cc * 8) = *(const bf16x8*)&Tf[r][cc * 8];
  }
}

__global__ __launch_bounds__(256) void k_proj(
    const float* __restrict__ x,
    const float* __restrict__ Wq,  const float* __restrict__ bq,
    const float* __restrict__ Wk,  const float* __restrict__ bk,
    const float* __restrict__ Wmq, const float* __restrict__ bmq,
    const float* __restrict__ Wmk, const float* __restrict__ bmk,
    unsigned short* __restrict__ q0w, unsigned short* __restrict__ k0w,
    unsigned short* __restrict__ fqw, unsigned short* __restrict__ fkw)
{
  const int tid = threadIdx.x;
  const int w = tid >> 6, l = tid & 63;
  const int l15 = l & 15, g = l >> 4;
  const long r0 = ((long)blockIdx.x * 4 + w) * 16;

  __shared__ unsigned short TqS[4][16][72];
  __shared__ unsigned short TfS[4][16][136];

  bf16x8 ax[2];
#pragma unroll
  for (int kk = 0; kk < 2; kk++)
    ax[kk] = cvt8(x + (r0 + l15) * 64 + kk * 32 + g * 8);

  proj_chain(ax, Wq, bq, Wmq, bmq, q0w, fqw, TqS[w], TfS[w], r0, l15, g, l);
  proj_chain(ax, Wk, bk, Wmk, bmk, k0w, fkw, TqS[w], TfS[w], r0, l15, g, l);
}

// ---------------------------------------------------------------------------
// Kernel 2: fk column-sum partials (bh, part): rows part*256..+255.
// ---------------------------------------------------------------------------
__global__ __launch_bounds__(256) void k_colsum1(const unsigned short* __restrict__ fkw)
{
  const int bh = blockIdx.x, part = blockIdx.y;
  const int tid = threadIdx.x;
  const int cg = tid & 15, rg = tid >> 4;
  const unsigned short* fkp = fkw + ((long)bh * NN + part * 256 + rg * 16) * 128 + cg * 8;

  float a8[8] = {0.f, 0.f, 0.f, 0.f, 0.f, 0.f, 0.f, 0.f};
#pragma unroll
  for (int r = 0; r < 16; r++) {
    bf16x8 v = *(const bf16x8*)(fkp + (long)r * 128);
#pragma unroll
    for (int j = 0; j < 8; j++) a8[j] += bf2f((unsigned short)v[j]);
  }
  __shared__ float red[16][132];
#pragma unroll
  for (int j = 0; j < 8; j++) red[rg][cg * 8 + j] = a8[j];
  __syncthreads();
  if (tid < 128) {
    float s = 0.f;
#pragma unroll
    for (int r = 0; r < 16; r++) s += red[r][tid];
    g_part[(bh * 8 + part) * 128 + tid] = s;
  }
}

// ---------------------------------------------------------------------------
// Kernel 3: row normalizers. Block = (bh, 128-row group), 4 waves.
// ---------------------------------------------------------------------------
__global__ __launch_bounds__(256) void k_norm(
    const unsigned short* __restrict__ q0w, const unsigned short* __restrict__ k0w,
    const unsigned short* __restrict__ fqw)
{
  const int bh = blockIdx.x, rg = blockIdx.y;
  const int tid = threadIdx.x;
  const int w = tid >> 6, l = tid & 63;
  const int l15 = l & 15, g = l >> 4;

  __shared__ float sfk[128];
  if (tid < 128) {
    float s = 0.f;
#pragma unroll
    for (int pt = 0; pt < 8; pt++) s += g_part[bh * 1024 + pt * 128 + tid];
    sfk[tid] = s;
  }
  __syncthreads();
  if (tid < 128) {
    const int row = rg * 128 + tid;
    const unsigned short* p = fqw + ((long)bh * NN + row) * 128;
    float d = 0.f;
#pragma unroll
    for (int i = 0; i < 16; i++) {
      bf16x8 v = *(const bf16x8*)(p + i * 8);
#pragma unroll
      for (int jj = 0; jj < 8; jj++) d += bf2f((unsigned short)v[jj]) * sfk[i * 8 + jj];
    }
    g_normP[bh * NN + row] = 1.0f / d;
  }

  const unsigned short* k0p = k0w + (long)bh * NN * 64;
#pragma unroll
  for (int tt = 0; tt < 2; tt++) {
    const int rb = rg * 128 + w * 32 + tt * 16;
    const unsigned short* qp = q0w + ((long)bh * NN + rb) * 64;
    bf16x8 a0 = *(const bf16x8*)(qp + l15 * 64 + g * 8);
    bf16x8 a1 = *(const bf16x8*)(qp + l15 * 64 + 32 + g * 8);
    float st[4] = {0.f, 0.f, 0.f, 0.f};
    for (int kt = 0; kt < 128; kt++) {
      const unsigned short* bp = k0p + (long)(kt * 16 + l15) * 64 + g * 8;
      f32x4 acc = {0.f, 0.f, 0.f, 0.f};
      acc = mfma16(a0, *(const bf16x8*)bp, acc);
      acc = mfma16(a1, *(const bf16x8*)(bp + 32), acc);
#pragma unroll
      for (int j = 0; j < 4; j++) st[j] += __expf(acc[j] * 0.125f);
    }
#pragma unroll
    for (int j = 0; j < 4; j++) {
      float v = st[j];
      v += __shfl_xor(v, 1, 16);
      v += __shfl_xor(v, 2, 16);
      v += __shfl_xor(v, 4, 16);
      v += __shfl_xor(v, 8, 16);
      if (l15 == 0) g_normT[bh * NN + rb + g * 4 + j] = 1.0f / v;
    }
  }
}

// ---------------------------------------------------------------------------
// Kernel 4: async-staged producer/consumer writer. Block = (bh, 16 rows),
// 8 waves: w0-3 producers, w4-7 storers. 64 chunks of 16 rows x 64 keys
// (32 pred + 32 true). Operand tiles staged transposed into LDS ring-3 via
// global_load_lds (2 chunks in flight, counted vmcnt). Output via LDS ring-4,
// storers 2 chunks behind, pure-store. 67 matched raw s_barriers.
// ---------------------------------------------------------------------------
__global__ __launch_bounds__(512, 2) void k_write(
    const unsigned short* __restrict__ q0w, const unsigned short* __restrict__ k0w,
    const unsigned short* __restrict__ fqw, const unsigned short* __restrict__ fkw,
    float* __restrict__ out)
{
  const int bh = blockIdx.x;          // 0..31
  const int rq = blockIdx.y;          // 0..127
  const int tid = threadIdx.x;
  const int w = tid >> 6, l = tid & 63;
  const int l15 = l & 15, g = l >> 4;
  const int qrow0 = rq * 16;

  // operand ring-3: transposed tile [colchunk][key], 16B slots. pred uses
  // 1024 slots (16 cc x 64 keys), true 512. 3 x 16KB = 48KB.
  __shared__ unsigned short opnd[3][8192];
  // output ring-4: 16 rows x 64 cols fp32 (+pad). 4 x ~4.3KB.
  __shared__ float obuf[4][16][68];

  const unsigned short* fkp = fkw + (long)bh * NN * 128;
  const unsigned short* k0p = k0w + (long)bh * NN * 64;
  const long ob_p = (long)bh * NN * NN + (long)qrow0 * NN;
  const long ob_t = ob_p + (long)NBH * NN * NN;

  if (w < 4) {
    // ======================= producer =======================
    const unsigned short* fqp = fqw + ((long)bh * NN + qrow0) * 128;
    const unsigned short* q0p = q0w + ((long)bh * NN + qrow0) * 64;
    bf16x8 afq[4], aq0[2];
#pragma unroll
    for (int kk = 0; kk < 4; kk++)
      afq[kk] = *(const bf16x8*)(fqp + l15 * 128 + kk * 32 + g * 8);
#pragma unroll
    for (int kk = 0; kk < 2; kk++)
      aq0[kk] = *(const bf16x8*)(q0p + l15 * 64 + kk * 32 + g * 8);
    float ip[4], it[4];
#pragma unroll
    for (int j = 0; j < 4; j++) {
      ip[j] = g_normP[bh * NN + qrow0 + g * 4 + j];
      it[j] = g_normT[bh * NN + qrow0 + g * 4 + j];
    }

    // stage chunk cs into opnd[cs%3], transposed: slot s=(cc*64+key) <- global
    // (key = s&63 = lane, colchunk = s>>6 = R). 4 (pred) / 2 (true) rounds/wave.
#define STAGE(CS) {                                                            \
      if ((CS) < 64) {                                                         \
        const int pl_ = (CS) >> 5;                                             \
        const long kb_ = (long)((CS) & 31) * 64;                               \
        unsigned short* dst_ = opnd[(CS) % 3];                                 \
        if (pl_ == 0) {                                                        \
          const unsigned short* src_ = fkp + (kb_ + l) * 128;                  \
          _Pragma("unroll")                                                    \
          for (int r_ = 0; r_ < 4; r_++) {                                     \
            const int R_ = w * 4 + r_;                                         \
            __builtin_amdgcn_global_load_lds(                                  \
                (const void*)(src_ + R_ * 8), (void*)(dst_ + R_ * 512),        \
                16, 0, 0);                                                     \
          }                                                                    \
        } else {                                                               \
          const unsigned short* src_ = k0p + (kb_ + l) * 64;                   \
          _Pragma("unroll")                                                    \
          for (int r_ = 0; r_ < 2; r_++) {                                     \
            const int R_ = w * 2 + r_;                                         \
            __builtin_amdgcn_global_load_lds(                                  \
                (const void*)(src_ + R_ * 8), (void*)(dst_ + R_ * 512),        \
                16, 0, 0);                                                     \
          }                                                                    \
        }                                                                      \
      }                                                                        \
    }

#define COMPUTE(C) {                                                           \
      const int pl_ = (C) >> 5;                                                \
      const unsigned short* sp_ = opnd[(C) % 3];                               \
      float (*ob_)[68] = obuf[(C) & 3];                                        \
      f32x4 acc_ = {0.f, 0.f, 0.f, 0.f};                                       \
      if (pl_ == 0) {                                                          \
        _Pragma("unroll")                                                      \
        for (int kk_ = 0; kk_ < 4; kk_++) {                                    \
          bf16x8 bk_ = *(const bf16x8*)(sp_ + ((kk_ * 4 + g) * 64 + w * 16 + l15) * 8); \
          acc_ = mfma16(afq[kk_], bk_, acc_);                                  \
        }                                                                      \
        _Pragma("unroll")                                                      \
        for (int j_ = 0; j_ < 4; j_++)                                         \
          ob_[g * 4 + j_][w * 16 + l15] = acc_[j_] * ip[j_];                   \
      } else {                                                                 \
        _Pragma("unroll")                                                      \
        for (int kk_ = 0; kk_ < 2; kk_++) {                                    \
          bf16x8 bk_ = *(const bf16x8*)(sp_ + ((kk_ * 4 + g) * 64 + w * 16 + l15) * 8); \
          acc_ = mfma16(aq0[kk_], bk_, acc_);                                  \
        }                                                                      \
        _Pragma("unroll")                                                      \
        for (int j_ = 0; j_ < 4; j_++)                                         \
          ob_[g * 4 + j_][w * 16 + l15] = __expf(acc_[j_] * 0.125f) * it[j_];  \
      }                                                                        \
    }

    STAGE(0);
    STAGE(1);
    asm volatile("s_waitcnt vmcnt(4)" ::: "memory");   // chunk 0 landed
    __builtin_amdgcn_sched_barrier(0);
    __builtin_amdgcn_s_barrier();
    __builtin_amdgcn_sched_barrier(0);

#pragma unroll 1
    for (int c = 0; c < 30; c++) {      // pred region: 4-round stages in flight
      STAGE(c + 2);
      COMPUTE(c);
      asm volatile("s_waitcnt vmcnt(4) lgkmcnt(0)" ::: "memory");  // c+1 landed
      __builtin_amdgcn_sched_barrier(0);
      __builtin_amdgcn_s_barrier();
      __builtin_amdgcn_sched_barrier(0);
    }
#pragma unroll 1
    for (int c = 30; c < 64; c++) {     // true region: 2-round stages in flight
      STAGE(c + 2);
      COMPUTE(c);
      asm volatile("s_waitcnt vmcnt(2) lgkmcnt(0)" ::: "memory");
      __builtin_amdgcn_sched_barrier(0);
      __builtin_amdgcn_s_barrier();
      __builtin_amdgcn_sched_barrier(0);
    }
    __builtin_amdgcn_s_barrier();       // drain 1
    __builtin_amdgcn_s_barrier();       // drain 2
#undef STAGE
#undef COMPUTE
  } else {
    // ======================= storer =======================
    const int sw = w - 4;
    const int row = sw * 4 + (l >> 4);
    const int col = (l & 15) * 4;
    __builtin_amdgcn_s_barrier();       // prologue
    __builtin_amdgcn_sched_barrier(0);
#pragma unroll 1
    for (int c = 0; c < 64; c++) {
      if (c >= 2) {
        const int s = c - 2;
        const int pl = s >> 5;
        const long kb = (long)(s & 31) * 64;
        f32x4 v = *(const f32x4*)&obuf[s & 3][row][col];
        *(f32x4*)(out + (pl ? ob_t : ob_p) + (long)row * NN + kb + col) = v;
      }
      __builtin_amdgcn_s_barrier();
      __builtin_amdgcn_sched_barrier(0);
    }
    {
      const int s = 62;
      f32x4 v = *(const f32x4*)&obuf[s & 3][row][col];
      *(f32x4*)(out + ob_t + (long)row * NN + (long)(s & 31) * 64 + col) = v;
    }
    __builtin_amdgcn_s_barrier();       // drain 1
    {
      const int s = 63;
      f32x4 v = *(const f32x4*)&obuf[s & 3][row][col];
      *(f32x4*)(out + ob_t + (long)row * NN + (long)(s & 31) * 64 + col) = v;
    }
    __builtin_amdgcn_s_barrier();       // drain 2
  }
}

extern "C" void kernel_launch(void* const* d_in, const int* in_sizes, int n_in,
                              void* d_out, int out_size, void* d_ws, size_t ws_size,
                              hipStream_t stream) {
  const float* x   = (const float*)d_in[0];
  const float* Wq  = (const float*)d_in[1];
  const float* bq  = (const float*)d_in[2];
  const float* Wk  = (const float*)d_in[3];
  const float* bk  = (const float*)d_in[4];
  const float* Wmq = (const float*)d_in[5];
  const float* bmq = (const float*)d_in[6];
  const float* Wmk = (const float*)d_in[7];
  const float* bmk = (const float*)d_in[8];
  float* out = (float*)d_out;

  // ws layout (bf16): q0[32][2048][64], k0[...], fq[32][2048][128], fk[...] = 48 MB
  unsigned short* q0w = (unsigned short*)d_ws;
  unsigned short* k0w = q0w + (long)NBH * NN * 64;
  unsigned short* fqw = k0w + (long)NBH * NN * 64;
  unsigned short* fkw = fqw + (long)NBH * NN * 128;

  hipLaunchKernelGGL(k_proj, dim3(1024), dim3(256), 0, stream,
                     x, Wq, bq, Wk, bk, Wmq, bmq, Wmk, bmk, q0w, k0w, fqw, fkw);
  hipLaunchKernelGGL(k_colsum1, dim3(NBH, 8), dim3(256), 0, stream, fkw);
  hipLaunchKernelGGL(k_norm, dim3(NBH, 16), dim3(256), 0, stream, q0w, k0w, fqw);
  hipLaunchKernelGGL(k_write, dim3(NBH, 128), dim3(512), 0, stream,
                     q0w, k0w, fqw, fkw, out);
}

// Round 12
// 572.852 us; speedup vs baseline: 1.1073x; 1.1073x over previous
//
#include <hip/hip_runtime.h>

// ---------------------------------------------------------------------------
// HedgeHog attention distillation map: pred = (fq.fk^T) rownorm, true = softmax(q0.k0^T/8)
// Output [2,2,16,2048,2048] fp32 = 1.07 GiB -> HBM-write-bound (~165us floor).
//
// v12: deep store-register rotation. Stores hold their source VGPRs until
// acked; rewriting them forces a WAR vmcnt wait. Fill (6.5 TB/s) stores one
// constant reg (no hazard); our kernels rotated ~2 regs -> ~2 TB/s cap across
// 11 structural variants. Fix: batch 8 ds_reads into 8 DISTINCT f32x4 regs,
// then 8 back-to-back stores (8KB/wave in flight); 4 blocks/CU (2x waves),
// staggered phase order per block; precomputed normalizers (k_norm).
// ---------------------------------------------------------------------------

typedef __attribute__((ext_vector_type(8))) short  bf16x8;
typedef __attribute__((ext_vector_type(4))) float  f32x4;

#define NN 2048
#define NBH 32

__device__ float g_part[NBH * 8 * 128];   // fk colsum partials
__device__ float g_normP[NBH * NN];       // 1 / pred row sum
__device__ float g_normT[NBH * NN];       // 1 / true row sum

__device__ __forceinline__ float bf2f(unsigned short u) {
  union { unsigned int i; float f; } v; v.i = ((unsigned int)u) << 16; return v.f;
}
__device__ __forceinline__ unsigned short f2bf(float f) {
  union { float f; unsigned int i; } v; v.f = f;
  unsigned int x = v.i;
  return (unsigned short)((x + 0x7FFFu + ((x >> 16) & 1u)) >> 16);  // RNE
}
__device__ __forceinline__ bf16x8 cvt8(const float* __restrict__ p) {
  bf16x8 v;
#pragma unroll
  for (int i = 0; i < 8; i++) v[i] = (short)f2bf(p[i]);
  return v;
}
__device__ __forceinline__ f32x4 mfma16(bf16x8 a, bf16x8 b, f32x4 c) {
  return __builtin_amdgcn_mfma_f32_16x16x32_bf16(a, b, c, 0, 0, 0);
}

// ---------------------------------------------------------------------------
// Kernel 1: projections + hedgehog features. One wave owns 16 rows.
// ---------------------------------------------------------------------------
__device__ __forceinline__ void proj_chain(
    const bf16x8 ax[2],
    const float* __restrict__ W1, const float* __restrict__ b1,
    const float* __restrict__ W2, const float* __restrict__ b2,
    unsigned short* __restrict__ o1w, unsigned short* __restrict__ o2w,
    unsigned short (*Tq)[72], unsigned short (*Tf)[136],
    long r0, int l15, int g, int l)
{
#pragma unroll
  for (int nt = 0; nt < 4; nt++) {
    f32x4 acc = {0.f, 0.f, 0.f, 0.f};
    acc = mfma16(ax[0], cvt8(W1 + (nt * 16 + l15) * 64 + g * 8), acc);
    acc = mfma16(ax[1], cvt8(W1 + (nt * 16 + l15) * 64 + 32 + g * 8), acc);
    float bv = b1[nt * 16 + l15];
#pragma unroll
    for (int j = 0; j < 4; j++)
      Tq[g * 4 + j][nt * 16 + l15] = f2bf(acc[j] + bv);   // C layout: row=(l>>4)*4+j, col=l&15
  }
#pragma unroll
  for (int i = 0; i < 2; i++) {
    int c = i * 64 + l;
    int r = c >> 3, cc = c & 7;
    *(bf16x8*)(o1w + (r0 + r) * 64 + cc * 8) = *(const bf16x8*)&Tq[r][cc * 8];
  }
  bf16x8 a1[2];
#pragma unroll
  for (int kk = 0; kk < 2; kk++)
    a1[kk] = *(const bf16x8*)&Tq[l15][kk * 32 + g * 8];
#pragma unroll
  for (int nt = 0; nt < 4; nt++) {
    f32x4 acc = {0.f, 0.f, 0.f, 0.f};
    acc = mfma16(a1[0], cvt8(W2 + (nt * 16 + l15) * 64 + g * 8), acc);
    acc = mfma16(a1[1], cvt8(W2 + (nt * 16 + l15) * 64 + 32 + g * 8), acc);
    float bv = b2[nt * 16 + l15];
#pragma unroll
    for (int j = 0; j < 4; j++) {
      float h = acc[j] + bv;
      Tf[g * 4 + j][nt * 16 + l15]      = f2bf(__expf(h));
      Tf[g * 4 + j][64 + nt * 16 + l15] = f2bf(__expf(-h));
    }
  }
#pragma unroll
  for (int i = 0; i < 4; i++) {
    int c = i * 64 + l;
    int r = c >> 4, cc = c & 15;
    *(bf16x8*)(o2w + (r0 + r) * 128 + cc * 8) = *(const bf16x8*)&Tf[r][cc * 8];
  }
}

__global__ __launch_bounds__(256) void k_proj(
    const float* __restrict__ x,
    const float* __restrict__ Wq,  const float* __restrict__ bq,
    const float* __restrict__ Wk,  const float* __restrict__ bk,
    const float* __restrict__ Wmq, const float* __restrict__ bmq,
    const float* __restrict__ Wmk, const float* __restrict__ bmk,
    unsigned short* __restrict__ q0w, unsigned short* __restrict__ k0w,
    unsigned short* __restrict__ fqw, unsigned short* __restrict__ fkw)
{
  const int tid = threadIdx.x;
  const int w = tid >> 6, l = tid & 63;
  const int l15 = l & 15, g = l >> 4;
  const long r0 = ((long)blockIdx.x * 4 + w) * 16;

  __shared__ unsigned short TqS[4][16][72];
  __shared__ unsigned short TfS[4][16][136];

  bf16x8 ax[2];
#pragma unroll
  for (int kk = 0; kk < 2; kk++)
    ax[kk] = cvt8(x + (r0 + l15) * 64 + kk * 32 + g * 8);

  proj_chain(ax, Wq, bq, Wmq, bmq, q0w, fqw, TqS[w], TfS[w], r0, l15, g, l);
  proj_chain(ax, Wk, bk, Wmk, bmk, k0w, fkw, TqS[w], TfS[w], r0, l15, g, l);
}

// ---------------------------------------------------------------------------
// Kernel 2: fk column-sum partials (bh, part): rows part*256..+255.
// ---------------------------------------------------------------------------
__global__ __launch_bounds__(256) void k_colsum1(const unsigned short* __restrict__ fkw)
{
  const int bh = blockIdx.x, part = blockIdx.y;
  const int tid = threadIdx.x;
  const int cg = tid & 15, rg = tid >> 4;
  const unsigned short* fkp = fkw + ((long)bh * NN + part * 256 + rg * 16) * 128 + cg * 8;

  float a8[8] = {0.f, 0.f, 0.f, 0.f, 0.f, 0.f, 0.f, 0.f};
#pragma unroll
  for (int r = 0; r < 16; r++) {
    bf16x8 v = *(const bf16x8*)(fkp + (long)r * 128);
#pragma unroll
    for (int j = 0; j < 8; j++) a8[j] += bf2f((unsigned short)v[j]);
  }
  __shared__ float red[16][132];
#pragma unroll
  for (int j = 0; j < 8; j++) red[rg][cg * 8 + j] = a8[j];
  __syncthreads();
  if (tid < 128) {
    float s = 0.f;
#pragma unroll
    for (int r = 0; r < 16; r++) s += red[r][tid];
    g_part[(bh * 8 + part) * 128 + tid] = s;
  }
}

// ---------------------------------------------------------------------------
// Kernel 3: row normalizers. Block = (bh, 128-row group), 4 waves.
// ---------------------------------------------------------------------------
__global__ __launch_bounds__(256) void k_norm(
    const unsigned short* __restrict__ q0w, const unsigned short* __restrict__ k0w,
    const unsigned short* __restrict__ fqw)
{
  const int bh = blockIdx.x, rg = blockIdx.y;
  const int tid = threadIdx.x;
  const int w = tid >> 6, l = tid & 63;
  const int l15 = l & 15, g = l >> 4;

  __shared__ float sfk[128];
  if (tid < 128) {
    float s = 0.f;
#pragma unroll
    for (int pt = 0; pt < 8; pt++) s += g_part[bh * 1024 + pt * 128 + tid];
    sfk[tid] = s;
  }
  __syncthreads();
  if (tid < 128) {
    const int row = rg * 128 + tid;
    const unsigned short* p = fqw + ((long)bh * NN + row) * 128;
    float d = 0.f;
#pragma unroll
    for (int i = 0; i < 16; i++) {
      bf16x8 v = *(const bf16x8*)(p + i * 8);
#pragma unroll
      for (int jj = 0; jj < 8; jj++) d += bf2f((unsigned short)v[jj]) * sfk[i * 8 + jj];
    }
    g_normP[bh * NN + row] = 1.0f / d;
  }

  const unsigned short* k0p = k0w + (long)bh * NN * 64;
#pragma unroll
  for (int tt = 0; tt < 2; tt++) {
    const int rb = rg * 128 + w * 32 + tt * 16;
    const unsigned short* qp = q0w + ((long)bh * NN + rb) * 64;
    bf16x8 a0 = *(const bf16x8*)(qp + l15 * 64 + g * 8);
    bf16x8 a1 = *(const bf16x8*)(qp + l15 * 64 + 32 + g * 8);
    float st[4] = {0.f, 0.f, 0.f, 0.f};
    for (int kt = 0; kt < 128; kt++) {
      const unsigned short* bp = k0p + (long)(kt * 16 + l15) * 64 + g * 8;
      f32x4 acc = {0.f, 0.f, 0.f, 0.f};
      acc = mfma16(a0, *(const bf16x8*)bp, acc);
      acc = mfma16(a1, *(const bf16x8*)(bp + 32), acc);
#pragma unroll
      for (int j = 0; j < 4; j++) st[j] += __expf(acc[j] * 0.125f);
    }
#pragma unroll
    for (int j = 0; j < 4; j++) {
      float v = st[j];
      v += __shfl_xor(v, 1, 16);
      v += __shfl_xor(v, 2, 16);
      v += __shfl_xor(v, 4, 16);
      v += __shfl_xor(v, 8, 16);
      if (l15 == 0) g_normT[bh * NN + rb + g * 4 + j] = 1.0f / v;
    }
  }
}

// ---------------------------------------------------------------------------
// Kernel 4: strip writer, batched stores. Block = (bh, 16 rows), 4 waves,
// 4 blocks/CU. 8 phases: {pred,true} x {quarter}, order staggered per block.
// Compute 16x512 normalized fp32 -> LDS; store: 8 ds_reads into 8 DISTINCT
// f32x4 regs then 8 back-to-back 1KB stores (deep WAR rotation).
// ---------------------------------------------------------------------------
__global__ __launch_bounds__(256, 4) void k_write(
    const unsigned short* __restrict__ q0w, const unsigned short* __restrict__ k0w,
    const unsigned short* __restrict__ fqw, const unsigned short* __restrict__ fkw,
    float* __restrict__ out)
{
  const int bh = blockIdx.x;          // 0..31
  const int rq = blockIdx.y;          // 0..127
  const int tid = threadIdx.x;
  const int w = tid >> 6, l = tid & 63;
  const int l15 = l & 15, g = l >> 4;
  const int rqe = (rq + bh * 37) & 127;
  const int qrow0 = rqe * 16;

  __shared__ float buf[16][516];      // 16x512 quarter-strip (stride 516: 2-way-free)

  const unsigned short* fqp = fqw + ((long)bh * NN + qrow0) * 128;
  const unsigned short* q0p = q0w + ((long)bh * NN + qrow0) * 64;
  const unsigned short* fkp = fkw + (long)bh * NN * 128;
  const unsigned short* k0p = k0w + (long)bh * NN * 64;

  bf16x8 afq[4], aq0[2];
#pragma unroll
  for (int kk = 0; kk < 4; kk++)
    afq[kk] = *(const bf16x8*)(fqp + l15 * 128 + kk * 32 + g * 8);
#pragma unroll
  for (int kk = 0; kk < 2; kk++)
    aq0[kk] = *(const bf16x8*)(q0p + l15 * 64 + kk * 32 + g * 8);

  float ip[4], it[4];
#pragma unroll
  for (int j = 0; j < 4; j++) {
    ip[j] = g_normP[bh * NN + qrow0 + g * 4 + j];
    it[j] = g_normT[bh * NN + qrow0 + g * 4 + j];
  }

  const long ob_p = (long)bh * NN * NN + (long)qrow0 * NN;
  const long ob_t = ob_p + (long)NBH * NN * NN;
  const int sw = (bh ^ rq) & 1;       // plane order stagger
  const int hw = rq & 3;              // quarter order stagger

  for (int ph = 0; ph < 8; ph++) {
    const int plane = (ph >> 2) ^ sw;
    const int q = ((ph & 3) + hw) & 3;
    // ---- compute 16 rows x 512 cols, normalized, into LDS ----
    if (plane == 0) {
#pragma unroll
      for (int tt = 0; tt < 8; tt++) {
        const int colh = w * 128 + tt * 16;
        const unsigned short* bp = fkp + (long)(q * 512 + colh + l15) * 128 + g * 8;
        f32x4 acc = {0.f, 0.f, 0.f, 0.f};
#pragma unroll
        for (int kk = 0; kk < 4; kk++)
          acc = mfma16(afq[kk], *(const bf16x8*)(bp + kk * 32), acc);
#pragma unroll
        for (int j = 0; j < 4; j++)
          buf[g * 4 + j][colh + l15] = acc[j] * ip[j];
      }
    } else {
#pragma unroll
      for (int tt = 0; tt < 8; tt++) {
        const int colh = w * 128 + tt * 16;
        const unsigned short* bp = k0p + (long)(q * 512 + colh + l15) * 64 + g * 8;
        f32x4 acc = {0.f, 0.f, 0.f, 0.f};
        acc = mfma16(aq0[0], *(const bf16x8*)bp, acc);
        acc = mfma16(aq0[1], *(const bf16x8*)(bp + 32), acc);
#pragma unroll
        for (int j = 0; j < 4; j++)
          buf[g * 4 + j][colh + l15] = __expf(acc[j] * 0.125f) * it[j];
      }
    }
    __syncthreads();
    // ---- batched store: 8 distinct regs, then 8 back-to-back 1KB stores ----
    {
      const long ob = (plane ? ob_t : ob_p) + q * 512;
      f32x4 v0, v1, v2, v3, v4, v5, v6, v7;
      v0 = *(const f32x4*)&buf[w * 4 + 0][l * 4];
      v1 = *(const f32x4*)&buf[w * 4 + 0][256 + l * 4];
      v2 = *(const f32x4*)&buf[w * 4 + 1][l * 4];
      v3 = *(const f32x4*)&buf[w * 4 + 1][256 + l * 4];
      v4 = *(const f32x4*)&buf[w * 4 + 2][l * 4];
      v5 = *(const f32x4*)&buf[w * 4 + 2][256 + l * 4];
      v6 = *(const f32x4*)&buf[w * 4 + 3][l * 4];
      v7 = *(const f32x4*)&buf[w * 4 + 3][256 + l * 4];
      asm volatile("s_waitcnt lgkmcnt(0)" ::: "memory");
      float* o0 = out + ob + (long)(w * 4 + 0) * NN + l * 4;
      float* o1 = out + ob + (long)(w * 4 + 1) * NN + l * 4;
      float* o2 = out + ob + (long)(w * 4 + 2) * NN + l * 4;
      float* o3 = out + ob + (long)(w * 4 + 3) * NN + l * 4;
      *(f32x4*)(o0)       = v0;
      *(f32x4*)(o0 + 256) = v1;
      *(f32x4*)(o1)       = v2;
      *(f32x4*)(o1 + 256) = v3;
      *(f32x4*)(o2)       = v4;
      *(f32x4*)(o2 + 256) = v5;
      *(f32x4*)(o3)       = v6;
      *(f32x4*)(o3 + 256) = v7;
    }
    __syncthreads();
  }
}

extern "C" void kernel_launch(void* const* d_in, const int* in_sizes, int n_in,
                              void* d_out, int out_size, void* d_ws, size_t ws_size,
                              hipStream_t stream) {
  const float* x   = (const float*)d_in[0];
  const float* Wq  = (const float*)d_in[1];
  const float* bq  = (const float*)d_in[2];
  const float* Wk  = (const float*)d_in[3];
  const float* bk  = (const float*)d_in[4];
  const float* Wmq = (const float*)d_in[5];
  const float* bmq = (const float*)d_in[6];
  const float* Wmk = (const float*)d_in[7];
  const float* bmk = (const float*)d_in[8];
  float* out = (float*)d_out;

  // ws layout (bf16): q0[32][2048][64], k0[...], fq[32][2048][128], fk[...] = 48 MB
  unsigned short* q0w = (unsigned short*)d_ws;
  unsigned short* k0w = q0w + (long)NBH * NN * 64;
  unsigned short* fqw = k0w + (long)NBH * NN * 64;
  unsigned short* fkw = fqw + (long)NBH * NN * 128;

  hipLaunchKernelGGL(k_proj, dim3(1024), dim3(256), 0, stream,
                     x, Wq, bq, Wk, bk, Wmq, bmq, Wmk, bmk, q0w, k0w, fqw, fkw);
  hipLaunchKernelGGL(k_colsum1, dim3(NBH, 8), dim3(256), 0, stream, fkw);
  hipLaunchKernelGGL(k_norm, dim3(NBH, 16), dim3(256), 0, stream, q0w, k0w, fqw);
  hipLaunchKernelGGL(k_write, dim3(NBH, 128), dim3(256), 0, stream,
                     q0w, k0w, fqw, fkw, out);
}

// Round 13
// 486.569 us; speedup vs baseline: 1.3036x; 1.1773x over previous
//
#include <hip/hip_runtime.h>

// ---------------------------------------------------------------------------
// HedgeHog attention distillation map: pred = (fq.fk^T) rownorm, true = softmax(q0.k0^T/8)
// Output [2,2,16,2048,2048] fp32 = 1.07 GiB -> HBM-write-bound.
//
// v13: operands LDS-RESIDENT for the whole block. Prior versions' operand
// loads ran at HBM latency because the 1.07GB write stream thrashes the
// per-XCD L2 (134MB of write lines vs 3MB read set) -> producer cadence
// ~2us/chunk -> 2 TB/s across 12 variants. Now: block = (bh, 128-key slab);
// fk+k0 slab staged ONCE to LDS (48KB); sweep all 2048 rows against it.
// Only global loads in the loop: 6KB/segment A-stream, prefetched one
// row-group (~2400cy) ahead. Stores via dbuf LDS transpose, 512B runs,
// raw s_barrier + lgkmcnt only (stores never drained).
// ---------------------------------------------------------------------------

typedef __attribute__((ext_vector_type(8))) short  bf16x8;
typedef __attribute__((ext_vector_type(4))) float  f32x4;

#define NN 2048
#define NBH 32

__device__ float g_part[NBH * 8 * 128];   // fk colsum partials
__device__ float g_normP[NBH * NN];       // 1 / pred row sum
__device__ float g_normT[NBH * NN];       // 1 / true row sum

__device__ __forceinline__ float bf2f(unsigned short u) {
  union { unsigned int i; float f; } v; v.i = ((unsigned int)u) << 16; return v.f;
}
__device__ __forceinline__ unsigned short f2bf(float f) {
  union { float f; unsigned int i; } v; v.f = f;
  unsigned int x = v.i;
  return (unsigned short)((x + 0x7FFFu + ((x >> 16) & 1u)) >> 16);  // RNE
}
__device__ __forceinline__ bf16x8 cvt8(const float* __restrict__ p) {
  bf16x8 v;
#pragma unroll
  for (int i = 0; i < 8; i++) v[i] = (short)f2bf(p[i]);
  return v;
}
__device__ __forceinline__ f32x4 mfma16(bf16x8 a, bf16x8 b, f32x4 c) {
  return __builtin_amdgcn_mfma_f32_16x16x32_bf16(a, b, c, 0, 0, 0);
}

// ---------------------------------------------------------------------------
// Kernel 1: projections + hedgehog features. One wave owns 16 rows.
// ---------------------------------------------------------------------------
__device__ __forceinline__ void proj_chain(
    const bf16x8 ax[2],
    const float* __restrict__ W1, const float* __restrict__ b1,
    const float* __restrict__ W2, const float* __restrict__ b2,
    unsigned short* __restrict__ o1w, unsigned short* __restrict__ o2w,
    unsigned short (*Tq)[72], unsigned short (*Tf)[136],
    long r0, int l15, int g, int l)
{
#pragma unroll
  for (int nt = 0; nt < 4; nt++) {
    f32x4 acc = {0.f, 0.f, 0.f, 0.f};
    acc = mfma16(ax[0], cvt8(W1 + (nt * 16 + l15) * 64 + g * 8), acc);
    acc = mfma16(ax[1], cvt8(W1 + (nt * 16 + l15) * 64 + 32 + g * 8), acc);
    float bv = b1[nt * 16 + l15];
#pragma unroll
    for (int j = 0; j < 4; j++)
      Tq[g * 4 + j][nt * 16 + l15] = f2bf(acc[j] + bv);   // C layout: row=(l>>4)*4+j, col=l&15
  }
#pragma unroll
  for (int i = 0; i < 2; i++) {
    int c = i * 64 + l;
    int r = c >> 3, cc = c & 7;
    *(bf16x8*)(o1w + (r0 + r) * 64 + cc * 8) = *(const bf16x8*)&Tq[r][cc * 8];
  }
  bf16x8 a1[2];
#pragma unroll
  for (int kk = 0; kk < 2; kk++)
    a1[kk] = *(const bf16x8*)&Tq[l15][kk * 32 + g * 8];
#pragma unroll
  for (int nt = 0; nt < 4; nt++) {
    f32x4 acc = {0.f, 0.f, 0.f, 0.f};
    acc = mfma16(a1[0], cvt8(W2 + (nt * 16 + l15) * 64 + g * 8), acc);
    acc = mfma16(a1[1], cvt8(W2 + (nt * 16 + l15) * 64 + 32 + g * 8), acc);
    float bv = b2[nt * 16 + l15];
#pragma unroll
    for (int j = 0; j < 4; j++) {
      float h = acc[j] + bv;
      Tf[g * 4 + j][nt * 16 + l15]      = f2bf(__expf(h));
      Tf[g * 4 + j][64 + nt * 16 + l15] = f2bf(__expf(-h));
    }
  }
#pragma unroll
  for (int i = 0; i < 4; i++) {
    int c = i * 64 + l;
    int r = c >> 4, cc = c & 15;
    *(bf16x8*)(o2w + (r0 + r) * 128 + cc * 8) = *(const bf16x8*)&Tf[r][cc * 8];
  }
}

__global__ __launch_bounds__(256) void k_proj(
    const float* __restrict__ x,
    const float* __restrict__ Wq,  const float* __restrict__ bq,
    const float* __restrict__ Wk,  const float* __restrict__ bk,
    const float* __restrict__ Wmq, const float* __restrict__ bmq,
    const float* __restrict__ Wmk, const float* __restrict__ bmk,
    unsigned short* __restrict__ q0w, unsigned short* __restrict__ k0w,
    unsigned short* __restrict__ fqw, unsigned short* __restrict__ fkw)
{
  const int tid = threadIdx.x;
  const int w = tid >> 6, l = tid & 63;
  const int l15 = l & 15, g = l >> 4;
  const long r0 = ((long)blockIdx.x * 4 + w) * 16;

  __shared__ unsigned short TqS[4][16][72];
  __shared__ unsigned short TfS[4][16][136];

  bf16x8 ax[2];
#pragma unroll
  for (int kk = 0; kk < 2; kk++)
    ax[kk] = cvt8(x + (r0 + l15) * 64 + kk * 32 + g * 8);

  proj_chain(ax, Wq, bq, Wmq, bmq, q0w, fqw, TqS[w], TfS[w], r0, l15, g, l);
  proj_chain(ax, Wk, bk, Wmk, bmk, k0w, fkw, TqS[w], TfS[w], r0, l15, g, l);
}

// ---------------------------------------------------------------------------
// Kernel 2: fk column-sum partials (bh, part): rows part*256..+255.
// ---------------------------------------------------------------------------
__global__ __launch_bounds__(256) void k_colsum1(const unsigned short* __restrict__ fkw)
{
  const int bh = blockIdx.x, part = blockIdx.y;
  const int tid = threadIdx.x;
  const int cg = tid & 15, rg = tid >> 4;
  const unsigned short* fkp = fkw + ((long)bh * NN + part * 256 + rg * 16) * 128 + cg * 8;

  float a8[8] = {0.f, 0.f, 0.f, 0.f, 0.f, 0.f, 0.f, 0.f};
#pragma unroll
  for (int r = 0; r < 16; r++) {
    bf16x8 v = *(const bf16x8*)(fkp + (long)r * 128);
#pragma unroll
    for (int j = 0; j < 8; j++) a8[j] += bf2f((unsigned short)v[j]);
  }
  __shared__ float red[16][132];
#pragma unroll
  for (int j = 0; j < 8; j++) red[rg][cg * 8 + j] = a8[j];
  __syncthreads();
  if (tid < 128) {
    float s = 0.f;
#pragma unroll
    for (int r = 0; r < 16; r++) s += red[r][tid];
    g_part[(bh * 8 + part) * 128 + tid] = s;
  }
}

// ---------------------------------------------------------------------------
// Kernel 3: row normalizers. Block = (bh, 128-row group), 4 waves.
// ---------------------------------------------------------------------------
__global__ __launch_bounds__(256) void k_norm(
    const unsigned short* __restrict__ q0w, const unsigned short* __restrict__ k0w,
    const unsigned short* __restrict__ fqw)
{
  const int bh = blockIdx.x, rg = blockIdx.y;
  const int tid = threadIdx.x;
  const int w = tid >> 6, l = tid & 63;
  const int l15 = l & 15, g = l >> 4;

  __shared__ float sfk[128];
  if (tid < 128) {
    float s = 0.f;
#pragma unroll
    for (int pt = 0; pt < 8; pt++) s += g_part[bh * 1024 + pt * 128 + tid];
    sfk[tid] = s;
  }
  __syncthreads();
  if (tid < 128) {
    const int row = rg * 128 + tid;
    const unsigned short* p = fqw + ((long)bh * NN + row) * 128;
    float d = 0.f;
#pragma unroll
    for (int i = 0; i < 16; i++) {
      bf16x8 v = *(const bf16x8*)(p + i * 8);
#pragma unroll
      for (int jj = 0; jj < 8; jj++) d += bf2f((unsigned short)v[jj]) * sfk[i * 8 + jj];
    }
    g_normP[bh * NN + row] = 1.0f / d;
  }

  const unsigned short* k0p = k0w + (long)bh * NN * 64;
#pragma unroll
  for (int tt = 0; tt < 2; tt++) {
    const int rb = rg * 128 + w * 32 + tt * 16;
    const unsigned short* qp = q0w + ((long)bh * NN + rb) * 64;
    bf16x8 a0 = *(const bf16x8*)(qp + l15 * 64 + g * 8);
    bf16x8 a1 = *(const bf16x8*)(qp + l15 * 64 + 32 + g * 8);
    float st[4] = {0.f, 0.f, 0.f, 0.f};
    for (int kt = 0; kt < 128; kt++) {
      const unsigned short* bp = k0p + (long)(kt * 16 + l15) * 64 + g * 8;
      f32x4 acc = {0.f, 0.f, 0.f, 0.f};
      acc = mfma16(a0, *(const bf16x8*)bp, acc);
      acc = mfma16(a1, *(const bf16x8*)(bp + 32), acc);
#pragma unroll
      for (int j = 0; j < 4; j++) st[j] += __expf(acc[j] * 0.125f);
    }
#pragma unroll
    for (int j = 0; j < 4; j++) {
      float v = st[j];
      v += __shfl_xor(v, 1, 16);
      v += __shfl_xor(v, 2, 16);
      v += __shfl_xor(v, 4, 16);
      v += __shfl_xor(v, 8, 16);
      if (l15 == 0) g_normT[bh * NN + rb + g * 4 + j] = 1.0f / v;
    }
  }
}

// ---------------------------------------------------------------------------
// Kernel 4: slab writer. Block = (bh, 128-key slab), 4 waves, 2 blocks/CU.
// Stage fk/k0 slab to LDS once; sweep 128 row-groups x {pred,true} segments.
// Per segment: prefetch next A-frags (global, 1 rg ahead) | compute from LDS
// | dbuf LDS transpose | lgkmcnt(0)+s_barrier | store 512B runs (never waited).
// ---------------------------------------------------------------------------
__global__ __launch_bounds__(256, 2) void k_write(
    const unsigned short* __restrict__ q0w, const unsigned short* __restrict__ k0w,
    const unsigned short* __restrict__ fqw, const unsigned short* __restrict__ fkw,
    float* __restrict__ out)
{
  const int bh = blockIdx.x;          // 0..31
  const int slab = blockIdx.y;        // 0..15 (128-key slab)
  const int tid = threadIdx.x;
  const int w = tid >> 6, l = tid & 63;
  const int l15 = l & 15, g = l >> 4;

  __shared__ unsigned short fkS[128][136];  // slab operands (padded rows)
  __shared__ unsigned short k0S[128][72];
  __shared__ float obuf[2][16][132];        // [0]=pred strip, [1]=true strip

  const unsigned short* fkp = fkw + ((long)bh * NN + slab * 128) * 128;
  const unsigned short* k0p = k0w + ((long)bh * NN + slab * 128) * 64;
  const unsigned short* fqb = fqw + (long)bh * NN * 128;
  const unsigned short* q0b = q0w + (long)bh * NN * 64;
  const float* npb = g_normP + bh * NN;
  const float* ntb = g_normT + bh * NN;
  const long ob_p = (long)bh * NN * NN + slab * 128;
  const long ob_t = ob_p + (long)NBH * NN * NN;

  // ---- stage slab operands once ----
#pragma unroll
  for (int i = 0; i < 8; i++) {
    int c = i * 256 + tid, r = c >> 4, cc = c & 15;
    *(bf16x8*)&fkS[r][cc * 8] = *(const bf16x8*)(fkp + (long)r * 128 + cc * 8);
  }
#pragma unroll
  for (int i = 0; i < 4; i++) {
    int c = i * 256 + tid, r = c >> 3, cc = c & 7;
    *(bf16x8*)&k0S[r][cc * 8] = *(const bf16x8*)(k0p + (long)r * 64 + cc * 8);
  }
  __syncthreads();

  // ---- A-frag register sets (double: current / next) ----
  bf16x8 aq[4], bq_[4], ak[2], bk_[2];
  f32x4 aip, ait, bip, bit;

#define PF(RG1, FQ, K0, IP, IT) {                                              \
    if ((RG1) < 128) {                                                         \
      const int qr_ = (RG1) * 16;                                              \
      _Pragma("unroll")                                                        \
      for (int kk = 0; kk < 4; kk++)                                           \
        FQ[kk] = *(const bf16x8*)(fqb + (long)(qr_ + l15) * 128 + kk * 32 + g * 8); \
      _Pragma("unroll")                                                        \
      for (int kk = 0; kk < 2; kk++)                                           \
        K0[kk] = *(const bf16x8*)(q0b + (long)(qr_ + l15) * 64 + kk * 32 + g * 8);  \
      IP = *(const f32x4*)(npb + qr_ + g * 4);                                 \
      IT = *(const f32x4*)(ntb + qr_ + g * 4);                                 \
    }                                                                          \
  }

#define CPRED(FQ, IP) {                                                        \
    _Pragma("unroll")                                                          \
    for (int t = 0; t < 2; t++) {                                              \
      const int key = w * 32 + t * 16 + l15;                                   \
      f32x4 acc = {0.f, 0.f, 0.f, 0.f};                                        \
      _Pragma("unroll")                                                        \
      for (int kk = 0; kk < 4; kk++)                                           \
        acc = mfma16(FQ[kk], *(const bf16x8*)&fkS[key][kk * 32 + g * 8], acc); \
      _Pragma("unroll")                                                        \
      for (int j = 0; j < 4; j++)                                              \
        obuf[0][g * 4 + j][key] = acc[j] * IP[j];                              \
    }                                                                          \
  }

#define CTRUE(K0, IT) {                                                        \
    _Pragma("unroll")                                                          \
    for (int t = 0; t < 2; t++) {                                              \
      const int key = w * 32 + t * 16 + l15;                                   \
      f32x4 acc = {0.f, 0.f, 0.f, 0.f};                                        \
      acc = mfma16(K0[0], *(const bf16x8*)&k0S[key][g * 8], acc);              \
      acc = mfma16(K0[1], *(const bf16x8*)&k0S[key][32 + g * 8], acc);         \
      _Pragma("unroll")                                                        \
      for (int j = 0; j < 4; j++)                                              \
        obuf[1][g * 4 + j][key] = __expf(acc[j] * 0.125f) * IT[j];             \
    }                                                                          \
  }

#define STORE(PL, RG2) {                                                       \
    const long ob = ((PL) ? ob_t : ob_p) + (long)((RG2) * 16) * NN;            \
    const int row0 = w * 4 + (l >> 5), col = (l & 31) * 4;                     \
    f32x4 v0 = *(const f32x4*)&obuf[PL][row0][col];                            \
    f32x4 v1 = *(const f32x4*)&obuf[PL][row0 + 2][col];                        \
    *(f32x4*)(out + ob + (long)row0 * NN + col)       = v0;                    \
    *(f32x4*)(out + ob + (long)(row0 + 2) * NN + col) = v1;                    \
  }

#define BODY(RG, FQ, K0, IP, IT, NFQ, NK0, NIP, NIT) {                         \
    /* --- pred segment --- */                                                 \
    PF((RG) + 1, NFQ, NK0, NIP, NIT);                                          \
    if ((RG) > 0) STORE(1, (RG) - 1);                                          \
    CPRED(FQ, IP);                                                             \
    asm volatile("s_waitcnt lgkmcnt(0)" ::: "memory");                         \
    __builtin_amdgcn_s_barrier();                                              \
    __builtin_amdgcn_sched_barrier(0);                                         \
    /* --- true segment --- */                                                 \
    STORE(0, RG);                                                              \
    CTRUE(K0, IT);                                                             \
    asm volatile("s_waitcnt lgkmcnt(0)" ::: "memory");                         \
    __builtin_amdgcn_s_barrier();                                              \
    __builtin_amdgcn_sched_barrier(0);                                         \
  }

  PF(0, aq, ak, aip, ait);            // row-group 0 operands

#pragma unroll 1
  for (int rg2 = 0; rg2 < 64; rg2++) {
    BODY(2 * rg2,     aq, ak, aip, ait, bq_, bk_, bip, bit);
    BODY(2 * rg2 + 1, bq_, bk_, bip, bit, aq, ak, aip, ait);
  }
  STORE(1, 127);                      // drain: last true strip

#undef PF
#undef CPRED
#undef CTRUE
#undef STORE
#undef BODY
}

extern "C" void kernel_launch(void* const* d_in, const int* in_sizes, int n_in,
                              void* d_out, int out_size, void* d_ws, size_t ws_size,
                              hipStream_t stream) {
  const float* x   = (const float*)d_in[0];
  const float* Wq  = (const float*)d_in[1];
  const float* bq  = (const float*)d_in[2];
  const float* Wk  = (const float*)d_in[3];
  const float* bk  = (const float*)d_in[4];
  const float* Wmq = (const float*)d_in[5];
  const float* bmq = (const float*)d_in[6];
  const float* Wmk = (const float*)d_in[7];
  const float* bmk = (const float*)d_in[8];
  float* out = (float*)d_out;

  // ws layout (bf16): q0[32][2048][64], k0[...], fq[32][2048][128], fk[...] = 48 MB
  unsigned short* q0w = (unsigned short*)d_ws;
  unsigned short* k0w = q0w + (long)NBH * NN * 64;
  unsigned short* fqw = k0w + (long)NBH * NN * 64;
  unsigned short* fkw = fqw + (long)NBH * NN * 128;

  hipLaunchKernelGGL(k_proj, dim3(1024), dim3(256), 0, stream,
                     x, Wq, bq, Wk, bk, Wmq, bmq, Wmk, bmk, q0w, k0w, fqw, fkw);
  hipLaunchKernelGGL(k_colsum1, dim3(NBH, 8), dim3(256), 0, stream, fkw);
  hipLaunchKernelGGL(k_norm, dim3(NBH, 16), dim3(256), 0, stream, q0w, k0w, fqw);
  hipLaunchKernelGGL(k_write, dim3(NBH, 16), dim3(256), 0, stream,
                     q0w, k0w, fqw, fkw, out);
}